// Round 9
// baseline (141.090 us; speedup 1.0000x reference)
//
#include <hip/hip_runtime.h>

static constexpr int N_NODES = 100000;
static constexpr int N_EDGES = 10000;
static constexpr int NNZ     = 1600000;

static constexpr int G1    = 256;          // scatter blocks
static constexpr int CHUNK = NNZ / G1;     // 6250
static constexpr int NRN   = 250;          // node ranges
static constexpr int RN    = 400;          // nodes per range
static constexpr int NRE   = 250;          // edge ranges
static constexpr int RE    = 40;           // edges per range
static constexpr int SLOT  = 64;           // entries per (range, scatter-block) slot
static constexpr int BLK   = 1024;
static constexpr int NW    = BLK / 64;     // 16 waves
static constexpr int GF    = 256;          // fused-kernel grid (= CU count, all co-resident)

// ---------------- ws layout (bytes) ----------------
// binN @ 0           : NRN*G1*SLOT u32 = 16,384,000
// binE @ 16,384,000  : NRE*G1*SLOT u32 = 16,384,000
// cntN @ 32,768,000  : NRN*G1 u32      = 256,000
// cntE @ 33,024,000  : NRE*G1 u32      = 256,000
// v1   @ 33,280,000  ; v2 +40,000 ; Binv +80,000 ; Dinv +120,000 (400KB) ; y +520,000 (400KB)
// bar  @ 34,200,000  : 4 u32 (reset by k_bin every call -> replay-safe)

// Agent-scope grid barrier: syncthreads drains all threads' stores to L2;
// threadfence (agent) writes dirty L2 back to the L3 coherence point; atomic
// arrive + spin; acquire fence invalidates stale L1/L2 before the next phase.
__device__ __forceinline__ void grid_barrier(unsigned* bar, unsigned target) {
    __syncthreads();
    if (threadIdx.x == 0) {
        __threadfence();   // release: L2 writeback (dirty set per phase is small)
        __hip_atomic_fetch_add(bar, 1u, __ATOMIC_RELEASE, __HIP_MEMORY_SCOPE_AGENT);
        while (__hip_atomic_load(bar, __ATOMIC_RELAXED, __HIP_MEMORY_SCOPE_AGENT) < target)
            __builtin_amdgcn_s_sleep(16);
        __threadfence();   // acquire: invalidate before consuming
    }
    __syncthreads();
}

// K1: deterministic-slot counting scatter (no global cursors, no memset) + bar reset.
__global__ __launch_bounds__(BLK) void k_bin(
        const int* __restrict__ nidx, const int* __restrict__ eidx,
        unsigned* __restrict__ binN, unsigned* __restrict__ binE,
        unsigned* __restrict__ cntN, unsigned* __restrict__ cntE,
        unsigned* __restrict__ bar) {
    __shared__ unsigned cN[NRN], cE[NRE];
    if (blockIdx.x == 0 && threadIdx.x < 4) bar[threadIdx.x] = 0u;
    for (int j = threadIdx.x; j < NRN; j += BLK) cN[j] = 0u;
    for (int j = threadIdx.x; j < NRE; j += BLK) cE[j] = 0u;
    __syncthreads();
    const int b = blockIdx.x;
    const int i0 = b * CHUNK, i1 = i0 + CHUNK;
    for (int i = i0 + threadIdx.x; i < i1; i += BLK) {
        int n = nidx[i], e = eidx[i];
        int rn = n / RN;
        int re = e / RE;
        unsigned pn = atomicAdd(&cN[rn], 1u);
        unsigned pe = atomicAdd(&cE[re], 1u);
        binN[((size_t)rn * G1 + b) * SLOT + pn] = ((unsigned)(n - rn * RN) << 14) | (unsigned)e;
        binE[((size_t)re * G1 + b) * SLOT + pe] = ((unsigned)(e - re * RE) << 17) | (unsigned)n;
    }
    __syncthreads();
    for (int j = threadIdx.x; j < NRN; j += BLK) cntN[(size_t)j * G1 + b] = cN[j];
    for (int j = threadIdx.x; j < NRE; j += BLK) cntE[(size_t)j * G1 + b] = cE[j];
}

// K2: all four aggregation phases, 3 lightweight agent-scope barriers.
__global__ __launch_bounds__(BLK) void k_fused(
        const unsigned* __restrict__ binN, const unsigned* __restrict__ binE,
        const unsigned* __restrict__ cntN, const unsigned* __restrict__ cntE,
        const float* __restrict__ x,
        const float* __restrict__ W1, const float* __restrict__ b1,
        const float* __restrict__ W2, const float* __restrict__ b2,
        float* __restrict__ v1, float* __restrict__ v2,
        float* __restrict__ Binv, float* __restrict__ Dinv, float* __restrict__ y,
        unsigned* __restrict__ bar, float* __restrict__ out) {
    __shared__ union {
        struct { unsigned scnt[G1]; float sS[NW][RE]; unsigned sC[NW][RE]; } e;              // ~6.2 KB
        struct { float sV[N_EDGES]; float sS[RN]; unsigned sC[RN]; unsigned scnt[G1];
                 float wgt[384]; } n;                                                         // ~45.8 KB
    } sm;
    const int b = blockIdx.x;
    const int t = threadIdx.x;

    // ---- Phase 0: edge pass 1 -> Binv, v1 ----
    if (b < NRE) {
        for (int j = t; j < NW * RE; j += BLK) { (&sm.e.sS[0][0])[j] = 0.0f; (&sm.e.sC[0][0])[j] = 0u; }
        if (t < G1) sm.e.scnt[t] = cntE[(size_t)b * G1 + t];
        __syncthreads();
        const int wv = t >> 6;
        const unsigned* base = binE + (size_t)b * G1 * SLOT;
        for (int j = t; j < G1 * SLOT; j += BLK) {
            int s = j & (SLOT - 1), bb = j >> 6;
            if ((unsigned)s < sm.e.scnt[bb]) {
                unsigned w = base[j];
                atomicAdd(&sm.e.sS[wv][w >> 17], x[w & 0x1FFFFu]);
                atomicAdd(&sm.e.sC[wv][w >> 17], 1u);
            }
        }
        __syncthreads();
        if (t < RE) {
            float s = 0.0f; unsigned c = 0u;
            #pragma unroll
            for (int k = 0; k < NW; ++k) { s += sm.e.sS[k][t]; c += sm.e.sC[k][t]; }
            float binv = (c > 0u) ? (1.0f / (float)c) : 0.0f;
            int e = b * RE + t;
            Binv[e] = binv;
            v1[e]   = s * binv;
        }
    }
    grid_barrier(bar + 0, GF);

    // ---- Phase 1: node pass 1 + Dinv + MLP -> y ----
    if (b < NRN) {
        for (int j = t; j < N_EDGES; j += BLK) sm.n.sV[j] = v1[j];
        if (t < RN) { sm.n.sS[t] = 0.0f; sm.n.sC[t] = 0u; }
        if (t < G1) sm.n.scnt[t] = cntN[(size_t)b * G1 + t];
        if (t < 128) {
            sm.n.wgt[t]       = W1[t];
            sm.n.wgt[128 + t] = b1[t];
            sm.n.wgt[256 + t] = W2[t];
        }
        __syncthreads();
        const unsigned* base = binN + (size_t)b * G1 * SLOT;
        for (int j = t; j < G1 * SLOT; j += BLK) {
            int s = j & (SLOT - 1), bb = j >> 6;
            if ((unsigned)s < sm.n.scnt[bb]) {
                unsigned w = base[j];
                unsigned nl = w >> 14;
                atomicAdd(&sm.n.sS[nl], sm.n.sV[w & 0x3FFFu]);
                atomicAdd(&sm.n.sC[nl], 1u);
            }
        }
        __syncthreads();
        if (t < RN) {
            unsigned c = sm.n.sC[t];
            float dinv = (c > 0u) ? (1.0f / (float)c) : 0.0f;
            int n = b * RN + t;
            Dinv[n] = dinv;
            float tt = sm.n.sS[t] * dinv;
            float acc = 0.0f;
            #pragma unroll
            for (int f = 0; f < 128; ++f) {
                float h = fmaf(tt, sm.n.wgt[f], sm.n.wgt[128 + f]);
                h = fmaxf(h, 0.0f);
                acc = fmaf(h, sm.n.wgt[256 + f], acc);
            }
            y[n] = acc;
        }
    }
    grid_barrier(bar + 1, GF);

    // ---- Phase 2: edge pass 2 -> v2 ----
    if (b < NRE) {
        for (int j = t; j < NW * RE; j += BLK) (&sm.e.sS[0][0])[j] = 0.0f;
        if (t < G1) sm.e.scnt[t] = cntE[(size_t)b * G1 + t];
        __syncthreads();
        const int wv = t >> 6;
        const unsigned* base = binE + (size_t)b * G1 * SLOT;
        for (int j = t; j < G1 * SLOT; j += BLK) {
            int s = j & (SLOT - 1), bb = j >> 6;
            if ((unsigned)s < sm.e.scnt[bb]) {
                unsigned w = base[j];
                atomicAdd(&sm.e.sS[wv][w >> 17], y[w & 0x1FFFFu]);
            }
        }
        __syncthreads();
        if (t < RE) {
            float s = 0.0f;
            #pragma unroll
            for (int k = 0; k < NW; ++k) s += sm.e.sS[k][t];
            int e = b * RE + t;
            v2[e] = s * Binv[e];
        }
    }
    grid_barrier(bar + 2, GF);

    // ---- Phase 3: node pass 2 + bias -> out ----
    if (b < NRN) {
        for (int j = t; j < N_EDGES; j += BLK) sm.n.sV[j] = v2[j];
        if (t < RN) sm.n.sS[t] = 0.0f;
        if (t < G1) sm.n.scnt[t] = cntN[(size_t)b * G1 + t];
        __syncthreads();
        const unsigned* base = binN + (size_t)b * G1 * SLOT;
        for (int j = t; j < G1 * SLOT; j += BLK) {
            int s = j & (SLOT - 1), bb = j >> 6;
            if ((unsigned)s < sm.n.scnt[bb]) {
                unsigned w = base[j];
                atomicAdd(&sm.n.sS[w >> 14], sm.n.sV[w & 0x3FFFu]);
            }
        }
        __syncthreads();
        if (t < RN) {
            int n = b * RN + t;
            out[n] = fmaf(sm.n.sS[t], Dinv[n], b2[0]);
        }
    }
}

extern "C" void kernel_launch(void* const* d_in, const int* in_sizes, int n_in,
                              void* d_out, int out_size, void* d_ws, size_t ws_size,
                              hipStream_t stream) {
    const float* x    = (const float*)d_in[0];
    const float* W1   = (const float*)d_in[1];
    const float* b1   = (const float*)d_in[2];
    const float* W2   = (const float*)d_in[3];
    const float* b2   = (const float*)d_in[4];
    const int*   nidx = (const int*)d_in[5];
    const int*   eidx = (const int*)d_in[6];
    float*       out  = (float*)d_out;

    char* ws = (char*)d_ws;
    unsigned* binN = (unsigned*)(ws + 0);
    unsigned* binE = (unsigned*)(ws + 16384000);
    unsigned* cntN = (unsigned*)(ws + 32768000);
    unsigned* cntE = (unsigned*)(ws + 33024000);
    float*    v1   = (float*)(ws + 33280000);
    float*    v2   = (float*)(ws + 33320000);
    float*    Binv = (float*)(ws + 33360000);
    float*    Dinv = (float*)(ws + 33400000);
    float*    y    = (float*)(ws + 33800000);
    unsigned* bar  = (unsigned*)(ws + 34200000);

    k_bin  <<<G1, BLK, 0, stream>>>(nidx, eidx, binN, binE, cntN, cntE, bar);
    k_fused<<<GF, BLK, 0, stream>>>(binN, binE, cntN, cntE, x, W1, b1, W2, b2,
                                    v1, v2, Binv, Dinv, y, bar, out);
}

// Round 10
// 100.362 us; speedup vs baseline: 1.4058x; 1.4058x over previous
//
#include <hip/hip_runtime.h>

static constexpr int N_NODES = 100000;
static constexpr int N_EDGES = 10000;
static constexpr int NNZ     = 1600000;

static constexpr int G1    = 256;          // scatter blocks
static constexpr int CHUNK = NNZ / G1;     // 6250
static constexpr int NRN   = 250;          // node ranges
static constexpr int RN    = 400;          // nodes per range
static constexpr int NRE   = 250;          // edge ranges
static constexpr int RE    = 40;           // edges per range
static constexpr int SLOT  = 64;           // entries per (range, scatter-block) slot
static constexpr int BLK   = 1024;
static constexpr int NW    = BLK / 64;     // 16 waves
static constexpr int GF    = 250;          // fused grid = active blocks (co-resident on 256 CUs)

// ---------------- ws layout (bytes) ----------------
// binN @ 0           : NRN*G1*SLOT u32 = 16,384,000
// binE @ 16,384,000  : NRE*G1*SLOT u32 = 16,384,000
// cntN @ 32,768,000  : NRN*G1 u32      = 256,000
// cntE @ 33,024,000  : NRE*G1 u32      = 256,000
// v1   @ 33,280,000 ; y @ 33,320,000 (400KB) ; v2 @ 33,720,000
// bar  @ 33,760,000  : 4 u32 (reset by k_bin -> replay-safe)

// Agent-scope (L3 write-through) accessors: sc1 ops complete at the coherence
// point, so no buffer_wbl2/buffer_inv L2 flushes are ever needed.
__device__ __forceinline__ float ld_a(const float* p) {
    return __hip_atomic_load(p, __ATOMIC_RELAXED, __HIP_MEMORY_SCOPE_AGENT);
}
__device__ __forceinline__ void st_a(float* p, float v) {
    __hip_atomic_store(p, v, __ATOMIC_RELAXED, __HIP_MEMORY_SCOPE_AGENT);
}

// Cheap grid barrier: __syncthreads drains each thread's vmcnt (sc1 stores are
// then in L3); one relaxed agent atomicAdd + spin. No cache-flush instructions.
__device__ __forceinline__ void grid_barrier(unsigned* bar, unsigned target) {
    __syncthreads();
    if (threadIdx.x == 0) {
        __hip_atomic_fetch_add(bar, 1u, __ATOMIC_RELAXED, __HIP_MEMORY_SCOPE_AGENT);
        while (__hip_atomic_load(bar, __ATOMIC_RELAXED, __HIP_MEMORY_SCOPE_AGENT) < target)
            __builtin_amdgcn_s_sleep(8);
    }
    __syncthreads();
}

// K1: deterministic-slot counting scatter (no cursors, no memset) + bar reset.
__global__ __launch_bounds__(BLK) void k_bin(
        const int* __restrict__ nidx, const int* __restrict__ eidx,
        unsigned* __restrict__ binN, unsigned* __restrict__ binE,
        unsigned* __restrict__ cntN, unsigned* __restrict__ cntE,
        unsigned* __restrict__ bar) {
    __shared__ unsigned cN[NRN], cE[NRE];
    if (blockIdx.x == 0 && threadIdx.x < 4) bar[threadIdx.x] = 0u;
    for (int j = threadIdx.x; j < NRN; j += BLK) cN[j] = 0u;
    for (int j = threadIdx.x; j < NRE; j += BLK) cE[j] = 0u;
    __syncthreads();
    const int b = blockIdx.x;
    const int i0 = b * CHUNK, i1 = i0 + CHUNK;
    for (int i = i0 + threadIdx.x; i < i1; i += BLK) {
        int n = nidx[i], e = eidx[i];
        int rn = n / RN;
        int re = e / RE;
        unsigned pn = atomicAdd(&cN[rn], 1u);
        unsigned pe = atomicAdd(&cE[re], 1u);
        binN[((size_t)rn * G1 + b) * SLOT + pn] = ((unsigned)(n - rn * RN) << 14) | (unsigned)e;
        binE[((size_t)re * G1 + b) * SLOT + pe] = ((unsigned)(e - re * RE) << 17) | (unsigned)n;
    }
    __syncthreads();
    for (int j = threadIdx.x; j < NRN; j += BLK) cntN[(size_t)j * G1 + b] = cN[j];
    for (int j = threadIdx.x; j < NRE; j += BLK) cntE[(size_t)j * G1 + b] = cE[j];
}

// K2: all four phases; 3 lightweight barriers; Binv/Dinv carried in registers.
__global__ __launch_bounds__(BLK) void k_fused(
        const unsigned* __restrict__ binN, const unsigned* __restrict__ binE,
        const unsigned* __restrict__ cntN, const unsigned* __restrict__ cntE,
        const float* __restrict__ x,
        const float* __restrict__ W1, const float* __restrict__ b1,
        const float* __restrict__ W2, const float* __restrict__ b2,
        float* __restrict__ v1, float* __restrict__ v2, float* __restrict__ y,
        unsigned* __restrict__ bar, float* __restrict__ out) {
    __shared__ union {
        struct { unsigned scnt[G1]; float sS[NW][RE]; unsigned sC[NW][RE]; } e;   // ~6.2 KB
        struct { float sV[N_EDGES]; float sS[RN]; unsigned sC[RN]; unsigned scnt[G1];
                 float wgt[384]; } n;                                              // ~45.8 KB
    } sm;
    const int b = blockIdx.x;
    const int t = threadIdx.x;

    float my_binv = 0.0f;   // valid for t < RE
    float my_dinv = 0.0f;   // valid for t < RN

    // ---- Phase 0: edge pass 1 -> v1 (Binv stays in register) ----
    {
        for (int j = t; j < NW * RE; j += BLK) { (&sm.e.sS[0][0])[j] = 0.0f; (&sm.e.sC[0][0])[j] = 0u; }
        if (t < G1) sm.e.scnt[t] = cntE[(size_t)b * G1 + t];
        __syncthreads();
        const int wv = t >> 6;
        const unsigned* base = binE + (size_t)b * G1 * SLOT;
        for (int j = t; j < G1 * SLOT; j += BLK) {
            int s = j & (SLOT - 1), bb = j >> 6;
            if ((unsigned)s < sm.e.scnt[bb]) {
                unsigned w = base[j];
                atomicAdd(&sm.e.sS[wv][w >> 17], x[w & 0x1FFFFu]);
                atomicAdd(&sm.e.sC[wv][w >> 17], 1u);
            }
        }
        __syncthreads();
        if (t < RE) {
            float s = 0.0f; unsigned c = 0u;
            #pragma unroll
            for (int k = 0; k < NW; ++k) { s += sm.e.sS[k][t]; c += sm.e.sC[k][t]; }
            my_binv = (c > 0u) ? (1.0f / (float)c) : 0.0f;
            st_a(&v1[b * RE + t], s * my_binv);
        }
    }
    grid_barrier(bar + 0, GF);

    // ---- Phase 1: node pass 1 + MLP -> y (Dinv stays in register) ----
    {
        for (int j = t; j < N_EDGES; j += BLK) sm.n.sV[j] = ld_a(&v1[j]);
        if (t < RN) { sm.n.sS[t] = 0.0f; sm.n.sC[t] = 0u; }
        if (t < G1) sm.n.scnt[t] = cntN[(size_t)b * G1 + t];
        if (t < 128) {
            sm.n.wgt[t]       = W1[t];
            sm.n.wgt[128 + t] = b1[t];
            sm.n.wgt[256 + t] = W2[t];
        }
        __syncthreads();
        const unsigned* base = binN + (size_t)b * G1 * SLOT;
        for (int j = t; j < G1 * SLOT; j += BLK) {
            int s = j & (SLOT - 1), bb = j >> 6;
            if ((unsigned)s < sm.n.scnt[bb]) {
                unsigned w = base[j];
                unsigned nl = w >> 14;
                atomicAdd(&sm.n.sS[nl], sm.n.sV[w & 0x3FFFu]);
                atomicAdd(&sm.n.sC[nl], 1u);
            }
        }
        __syncthreads();
        if (t < RN) {
            unsigned c = sm.n.sC[t];
            my_dinv = (c > 0u) ? (1.0f / (float)c) : 0.0f;
            float tt = sm.n.sS[t] * my_dinv;
            float acc = 0.0f;
            #pragma unroll
            for (int f = 0; f < 128; ++f) {
                float h = fmaf(tt, sm.n.wgt[f], sm.n.wgt[128 + f]);
                h = fmaxf(h, 0.0f);
                acc = fmaf(h, sm.n.wgt[256 + f], acc);
            }
            st_a(&y[b * RN + t], acc);
        }
    }
    grid_barrier(bar + 1, GF);

    // ---- Phase 2: edge pass 2 -> v2 ----
    {
        for (int j = t; j < NW * RE; j += BLK) (&sm.e.sS[0][0])[j] = 0.0f;
        if (t < G1) sm.e.scnt[t] = cntE[(size_t)b * G1 + t];
        __syncthreads();
        const int wv = t >> 6;
        const unsigned* base = binE + (size_t)b * G1 * SLOT;
        for (int j = t; j < G1 * SLOT; j += BLK) {
            int s = j & (SLOT - 1), bb = j >> 6;
            if ((unsigned)s < sm.e.scnt[bb]) {
                unsigned w = base[j];
                atomicAdd(&sm.e.sS[wv][w >> 17], ld_a(&y[w & 0x1FFFFu]));
            }
        }
        __syncthreads();
        if (t < RE) {
            float s = 0.0f;
            #pragma unroll
            for (int k = 0; k < NW; ++k) s += sm.e.sS[k][t];
            st_a(&v2[b * RE + t], s * my_binv);
        }
    }
    grid_barrier(bar + 2, GF);

    // ---- Phase 3: node pass 2 + bias -> out ----
    {
        for (int j = t; j < N_EDGES; j += BLK) sm.n.sV[j] = ld_a(&v2[j]);
        if (t < RN) sm.n.sS[t] = 0.0f;
        if (t < G1) sm.n.scnt[t] = cntN[(size_t)b * G1 + t];
        __syncthreads();
        const unsigned* base = binN + (size_t)b * G1 * SLOT;
        for (int j = t; j < G1 * SLOT; j += BLK) {
            int s = j & (SLOT - 1), bb = j >> 6;
            if ((unsigned)s < sm.n.scnt[bb]) {
                unsigned w = base[j];
                atomicAdd(&sm.n.sS[w >> 14], sm.n.sV[w & 0x3FFFu]);
            }
        }
        __syncthreads();
        if (t < RN) {
            out[b * RN + t] = fmaf(sm.n.sS[t], my_dinv, b2[0]);
        }
    }
}

extern "C" void kernel_launch(void* const* d_in, const int* in_sizes, int n_in,
                              void* d_out, int out_size, void* d_ws, size_t ws_size,
                              hipStream_t stream) {
    const float* x    = (const float*)d_in[0];
    const float* W1   = (const float*)d_in[1];
    const float* b1   = (const float*)d_in[2];
    const float* W2   = (const float*)d_in[3];
    const float* b2   = (const float*)d_in[4];
    const int*   nidx = (const int*)d_in[5];
    const int*   eidx = (const int*)d_in[6];
    float*       out  = (float*)d_out;

    char* ws = (char*)d_ws;
    unsigned* binN = (unsigned*)(ws + 0);
    unsigned* binE = (unsigned*)(ws + 16384000);
    unsigned* cntN = (unsigned*)(ws + 32768000);
    unsigned* cntE = (unsigned*)(ws + 33024000);
    float*    v1   = (float*)(ws + 33280000);
    float*    y    = (float*)(ws + 33320000);
    float*    v2   = (float*)(ws + 33720000);
    unsigned* bar  = (unsigned*)(ws + 33760000);

    k_bin  <<<G1, BLK, 0, stream>>>(nidx, eidx, binN, binE, cntN, cntE, bar);
    k_fused<<<GF, BLK, 0, stream>>>(binN, binE, cntN, cntE, x, W1, b1, W2, b2,
                                    v1, v2, y, bar, out);
}

// Round 11
// 88.464 us; speedup vs baseline: 1.5949x; 1.1345x over previous
//
#include <hip/hip_runtime.h>

static constexpr int N_NODES = 100000;
static constexpr int N_EDGES = 10000;
static constexpr int NNZ     = 1600000;

static constexpr int G1    = 256;          // scatter blocks
static constexpr int CHUNK = NNZ / G1;     // 6250
static constexpr int NRN   = 250;          // node ranges
static constexpr int RN    = 400;          // nodes per range
static constexpr int NRE   = 250;          // edge ranges
static constexpr int RE    = 40;           // edges per range
static constexpr int SLOT  = 64;           // entries per (range, scatter-block) slot
static constexpr int BLK   = 1024;
static constexpr int NW    = BLK / 64;     // 16 waves
static constexpr int GF    = 250;          // fused grid (co-resident on 256 CUs)
static constexpr int NBAR  = 8;            // distributed barrier sub-counters
static constexpr int BARSTRIDE = 32;       // u32s between counters (128 B, own cacheline)

// ---------------- ws layout (bytes) ----------------
// binN @ 0           : NRN*G1*SLOT u32 = 16,384,000
// binE @ 16,384,000  : NRE*G1*SLOT u32 = 16,384,000
// cntN @ 32,768,000  : NRN*G1 u32      = 256,000
// cntE @ 33,024,000  : NRE*G1 u32      = 256,000
// v1   @ 33,280,000 ; y @ 33,320,000 (400KB) ; v2 @ 33,720,000
// bar  @ 33,760,000  : 3 phases * NBAR * BARSTRIDE u32 = 3,072 B (reset by k_bin)

__device__ __forceinline__ float ld_a(const float* p) {
    return __hip_atomic_load(p, __ATOMIC_RELAXED, __HIP_MEMORY_SCOPE_AGENT);
}
__device__ __forceinline__ void st_a(float* p, float v) {
    __hip_atomic_store(p, v, __ATOMIC_RELAXED, __HIP_MEMORY_SCOPE_AGENT);
}

// Distributed grid barrier: arrivals spread over 8 padded counters (parallel
// RMW chains); polls are read-only sweeps of the 8 lines. No cache flushes.
// __syncthreads drains vmcnt, so all prior sc1 stores are at L3 before arrival.
__device__ __forceinline__ void grid_barrier(unsigned* bar, int phase) {
    __syncthreads();
    if (threadIdx.x == 0) {
        unsigned* cnt = bar + (size_t)phase * NBAR * BARSTRIDE;
        __hip_atomic_fetch_add(cnt + (blockIdx.x & (NBAR - 1)) * BARSTRIDE, 1u,
                               __ATOMIC_RELAXED, __HIP_MEMORY_SCOPE_AGENT);
        unsigned sum;
        do {
            __builtin_amdgcn_s_sleep(2);
            sum = 0u;
            #pragma unroll
            for (int g = 0; g < NBAR; ++g)
                sum += __hip_atomic_load(cnt + g * BARSTRIDE,
                                         __ATOMIC_RELAXED, __HIP_MEMORY_SCOPE_AGENT);
        } while (sum < (unsigned)GF);
    }
    __syncthreads();
}

// K1: deterministic-slot counting scatter (no cursors, no memset) + bar reset.
__global__ __launch_bounds__(BLK) void k_bin(
        const int* __restrict__ nidx, const int* __restrict__ eidx,
        unsigned* __restrict__ binN, unsigned* __restrict__ binE,
        unsigned* __restrict__ cntN, unsigned* __restrict__ cntE,
        unsigned* __restrict__ bar) {
    __shared__ unsigned cN[NRN], cE[NRE];
    if (blockIdx.x == 0 && threadIdx.x < 3 * NBAR * BARSTRIDE) bar[threadIdx.x] = 0u;
    for (int j = threadIdx.x; j < NRN; j += BLK) cN[j] = 0u;
    for (int j = threadIdx.x; j < NRE; j += BLK) cE[j] = 0u;
    __syncthreads();
    const int b = blockIdx.x;
    const int i0 = b * CHUNK, i1 = i0 + CHUNK;
    for (int i = i0 + threadIdx.x; i < i1; i += BLK) {
        int n = nidx[i], e = eidx[i];
        int rn = n / RN;
        int re = e / RE;
        unsigned pn = atomicAdd(&cN[rn], 1u);
        unsigned pe = atomicAdd(&cE[re], 1u);
        binN[((size_t)rn * G1 + b) * SLOT + pn] = ((unsigned)(n - rn * RN) << 14) | (unsigned)e;
        binE[((size_t)re * G1 + b) * SLOT + pe] = ((unsigned)(e - re * RE) << 17) | (unsigned)n;
    }
    __syncthreads();
    for (int j = threadIdx.x; j < NRN; j += BLK) cntN[(size_t)j * G1 + b] = cN[j];
    for (int j = threadIdx.x; j < NRE; j += BLK) cntE[(size_t)j * G1 + b] = cE[j];
}

// K2: all four phases; 3 distributed barriers; Binv/Dinv carried in registers.
__global__ __launch_bounds__(BLK) void k_fused(
        const unsigned* __restrict__ binN, const unsigned* __restrict__ binE,
        const unsigned* __restrict__ cntN, const unsigned* __restrict__ cntE,
        const float* __restrict__ x,
        const float* __restrict__ W1, const float* __restrict__ b1,
        const float* __restrict__ W2, const float* __restrict__ b2,
        float* __restrict__ v1, float* __restrict__ v2, float* __restrict__ y,
        unsigned* __restrict__ bar, float* __restrict__ out) {
    __shared__ union {
        struct { unsigned scnt[G1]; float sS[NW][RE]; unsigned sC[NW][RE]; } e;   // ~6.2 KB
        struct { float sV[N_EDGES]; float sS[RN]; unsigned sC[RN]; unsigned scnt[G1];
                 float wgt[384]; } n;                                              // ~45.8 KB
    } sm;
    const int b = blockIdx.x;
    const int t = threadIdx.x;

    float my_binv = 0.0f;   // valid for t < RE
    float my_dinv = 0.0f;   // valid for t < RN

    // ---- Phase 0: edge pass 1 -> v1 (Binv stays in register) ----
    {
        for (int j = t; j < NW * RE; j += BLK) { (&sm.e.sS[0][0])[j] = 0.0f; (&sm.e.sC[0][0])[j] = 0u; }
        if (t < G1) sm.e.scnt[t] = cntE[(size_t)b * G1 + t];
        __syncthreads();
        const int wv = t >> 6;
        const unsigned* base = binE + (size_t)b * G1 * SLOT;
        for (int j = t; j < G1 * SLOT; j += BLK) {
            int s = j & (SLOT - 1), bb = j >> 6;
            if ((unsigned)s < sm.e.scnt[bb]) {
                unsigned w = base[j];
                atomicAdd(&sm.e.sS[wv][w >> 17], x[w & 0x1FFFFu]);
                atomicAdd(&sm.e.sC[wv][w >> 17], 1u);
            }
        }
        __syncthreads();
        if (t < RE) {
            float s = 0.0f; unsigned c = 0u;
            #pragma unroll
            for (int k = 0; k < NW; ++k) { s += sm.e.sS[k][t]; c += sm.e.sC[k][t]; }
            my_binv = (c > 0u) ? (1.0f / (float)c) : 0.0f;
            st_a(&v1[b * RE + t], s * my_binv);
        }
    }
    grid_barrier(bar, 0);

    // ---- Phase 1: node pass 1 + MLP -> y (Dinv stays in register) ----
    {
        for (int j = t; j < N_EDGES; j += BLK) sm.n.sV[j] = ld_a(&v1[j]);
        if (t < RN) { sm.n.sS[t] = 0.0f; sm.n.sC[t] = 0u; }
        if (t < G1) sm.n.scnt[t] = cntN[(size_t)b * G1 + t];
        if (t < 128) {
            sm.n.wgt[t]       = W1[t];
            sm.n.wgt[128 + t] = b1[t];
            sm.n.wgt[256 + t] = W2[t];
        }
        __syncthreads();
        const unsigned* base = binN + (size_t)b * G1 * SLOT;
        for (int j = t; j < G1 * SLOT; j += BLK) {
            int s = j & (SLOT - 1), bb = j >> 6;
            if ((unsigned)s < sm.n.scnt[bb]) {
                unsigned w = base[j];
                unsigned nl = w >> 14;
                atomicAdd(&sm.n.sS[nl], sm.n.sV[w & 0x3FFFu]);
                atomicAdd(&sm.n.sC[nl], 1u);
            }
        }
        __syncthreads();
        if (t < RN) {
            unsigned c = sm.n.sC[t];
            my_dinv = (c > 0u) ? (1.0f / (float)c) : 0.0f;
            float tt = sm.n.sS[t] * my_dinv;
            float acc = 0.0f;
            #pragma unroll
            for (int f = 0; f < 128; ++f) {
                float h = fmaf(tt, sm.n.wgt[f], sm.n.wgt[128 + f]);
                h = fmaxf(h, 0.0f);
                acc = fmaf(h, sm.n.wgt[256 + f], acc);
            }
            st_a(&y[b * RN + t], acc);
        }
    }
    grid_barrier(bar, 1);

    // ---- Phase 2: edge pass 2 -> v2 ----
    {
        for (int j = t; j < NW * RE; j += BLK) (&sm.e.sS[0][0])[j] = 0.0f;
        if (t < G1) sm.e.scnt[t] = cntE[(size_t)b * G1 + t];
        __syncthreads();
        const int wv = t >> 6;
        const unsigned* base = binE + (size_t)b * G1 * SLOT;
        for (int j = t; j < G1 * SLOT; j += BLK) {
            int s = j & (SLOT - 1), bb = j >> 6;
            if ((unsigned)s < sm.e.scnt[bb]) {
                unsigned w = base[j];
                atomicAdd(&sm.e.sS[wv][w >> 17], ld_a(&y[w & 0x1FFFFu]));
            }
        }
        __syncthreads();
        if (t < RE) {
            float s = 0.0f;
            #pragma unroll
            for (int k = 0; k < NW; ++k) s += sm.e.sS[k][t];
            st_a(&v2[b * RE + t], s * my_binv);
        }
    }
    grid_barrier(bar, 2);

    // ---- Phase 3: node pass 2 + bias -> out ----
    {
        for (int j = t; j < N_EDGES; j += BLK) sm.n.sV[j] = ld_a(&v2[j]);
        if (t < RN) sm.n.sS[t] = 0.0f;
        if (t < G1) sm.n.scnt[t] = cntN[(size_t)b * G1 + t];
        __syncthreads();
        const unsigned* base = binN + (size_t)b * G1 * SLOT;
        for (int j = t; j < G1 * SLOT; j += BLK) {
            int s = j & (SLOT - 1), bb = j >> 6;
            if ((unsigned)s < sm.n.scnt[bb]) {
                unsigned w = base[j];
                atomicAdd(&sm.n.sS[w >> 14], sm.n.sV[w & 0x3FFFu]);
            }
        }
        __syncthreads();
        if (t < RN) {
            out[b * RN + t] = fmaf(sm.n.sS[t], my_dinv, b2[0]);
        }
    }
}

extern "C" void kernel_launch(void* const* d_in, const int* in_sizes, int n_in,
                              void* d_out, int out_size, void* d_ws, size_t ws_size,
                              hipStream_t stream) {
    const float* x    = (const float*)d_in[0];
    const float* W1   = (const float*)d_in[1];
    const float* b1   = (const float*)d_in[2];
    const float* W2   = (const float*)d_in[3];
    const float* b2   = (const float*)d_in[4];
    const int*   nidx = (const int*)d_in[5];
    const int*   eidx = (const int*)d_in[6];
    float*       out  = (float*)d_out;

    char* ws = (char*)d_ws;
    unsigned* binN = (unsigned*)(ws + 0);
    unsigned* binE = (unsigned*)(ws + 16384000);
    unsigned* cntN = (unsigned*)(ws + 32768000);
    unsigned* cntE = (unsigned*)(ws + 33024000);
    float*    v1   = (float*)(ws + 33280000);
    float*    y    = (float*)(ws + 33320000);
    float*    v2   = (float*)(ws + 33720000);
    unsigned* bar  = (unsigned*)(ws + 33760000);

    k_bin  <<<G1, BLK, 0, stream>>>(nidx, eidx, binN, binE, cntN, cntE, bar);
    k_fused<<<GF, BLK, 0, stream>>>(binN, binE, cntN, cntE, x, W1, b1, W2, b2,
                                    v1, v2, y, bar, out);
}

// Round 12
// 85.007 us; speedup vs baseline: 1.6597x; 1.0407x over previous
//
#include <hip/hip_runtime.h>

static constexpr int N_NODES = 100000;
static constexpr int N_EDGES = 10000;
static constexpr int NNZ     = 1600000;

static constexpr int G1    = 256;          // scatter blocks
static constexpr int CHUNK = NNZ / G1;     // 6250
static constexpr int NRN   = 250;          // node ranges (= GF)
static constexpr int RN    = 400;          // nodes per range
static constexpr int NRE   = 250;          // edge ranges (= GF)
static constexpr int RE    = 40;           // edges per range
static constexpr int SLOT  = 64;           // entries per (range, scatter-block) slot
static constexpr int BLK   = 1024;
static constexpr int NW    = 16;           // waves per block
static constexpr int GF    = 250;          // fused grid (co-resident)

// ---------------- ws layout (bytes) ----------------
// binN @ 0           : 16,384,000
// binE @ 16,384,000  : 16,384,000
// cntN @ 32,768,000  : 256,000
// cntE @ 33,024,000  : 256,000
// v1   @ 33,280,000  : 40,000
// v2   @ 33,320,000  : 40,000
// P_S  @ 33,360,000  : GF*N_EDGES f = 10,000,000  (edge partials from push)
// bar  @ 43,360,000  : counters 3*8*32 u32 + flags 3*32 u32 (reset by k_bin)

__device__ __forceinline__ float ld_a(const float* p) {
    return __hip_atomic_load(p, __ATOMIC_RELAXED, __HIP_MEMORY_SCOPE_AGENT);
}
__device__ __forceinline__ void st_a(float* p, float v) {
    __hip_atomic_store(p, v, __ATOMIC_RELAXED, __HIP_MEMORY_SCOPE_AGENT);
}

// Split barrier. arrive: syncthreads (drains vmcnt -> sc1 stores at L3) + one
// distributed counter add. wait: master (block 0) sums 8 counters, sets a single
// release flag; everyone else polls the flag (read-only line). No cache flushes.
__device__ __forceinline__ void bar_arrive(unsigned* bar, int phase) {
    __syncthreads();
    if (threadIdx.x == 0)
        __hip_atomic_fetch_add(bar + phase * 256 + (blockIdx.x & 7) * 32, 1u,
                               __ATOMIC_RELAXED, __HIP_MEMORY_SCOPE_AGENT);
}
__device__ __forceinline__ void bar_wait(unsigned* bar, int phase) {
    if (threadIdx.x == 0) {
        unsigned* flag = bar + 768 + phase * 32;
        if (blockIdx.x == 0) {
            unsigned* cnt = bar + phase * 256;
            unsigned sum;
            do {
                __builtin_amdgcn_s_sleep(2);
                sum = 0u;
                #pragma unroll
                for (int g = 0; g < 8; ++g)
                    sum += __hip_atomic_load(cnt + g * 32, __ATOMIC_RELAXED,
                                             __HIP_MEMORY_SCOPE_AGENT);
            } while (sum < (unsigned)GF);
            __hip_atomic_store(flag, 1u, __ATOMIC_RELAXED, __HIP_MEMORY_SCOPE_AGENT);
        } else {
            while (__hip_atomic_load(flag, __ATOMIC_RELAXED,
                                     __HIP_MEMORY_SCOPE_AGENT) == 0u)
                __builtin_amdgcn_s_sleep(2);
        }
    }
    __syncthreads();
}

// K1: deterministic-slot counting scatter + barrier reset.
__global__ __launch_bounds__(BLK) void k_bin(
        const int* __restrict__ nidx, const int* __restrict__ eidx,
        unsigned* __restrict__ binN, unsigned* __restrict__ binE,
        unsigned* __restrict__ cntN, unsigned* __restrict__ cntE,
        unsigned* __restrict__ bar) {
    __shared__ unsigned cN[NRN], cE[NRE];
    if (blockIdx.x == 0 && threadIdx.x < 896) bar[threadIdx.x] = 0u;
    for (int j = threadIdx.x; j < NRN; j += BLK) cN[j] = 0u;
    for (int j = threadIdx.x; j < NRE; j += BLK) cE[j] = 0u;
    __syncthreads();
    const int b = blockIdx.x;
    const int i0 = b * CHUNK, i1 = i0 + CHUNK;
    for (int i = i0 + threadIdx.x; i < i1; i += BLK) {
        int n = nidx[i], e = eidx[i];
        int rn = n / RN;
        int re = e / RE;
        unsigned pn = atomicAdd(&cN[rn], 1u);
        unsigned pe = atomicAdd(&cE[re], 1u);
        binN[((size_t)rn * G1 + b) * SLOT + pn] = ((unsigned)(n - rn * RN) << 14) | (unsigned)e;
        binE[((size_t)re * G1 + b) * SLOT + pe] = ((unsigned)(e - re * RE) << 17) | (unsigned)n;
    }
    __syncthreads();
    for (int j = threadIdx.x; j < NRN; j += BLK) cntN[(size_t)j * G1 + b] = cN[j];
    for (int j = threadIdx.x; j < NRE; j += BLK) cntE[(size_t)j * G1 + b] = cE[j];
}

// K2: A(edge1) | bar | B(node1+MLP+push) | bar | C(partial reduce) | bar | D(node2)
__global__ __launch_bounds__(BLK) void k_fused(
        const unsigned* __restrict__ binN, const unsigned* __restrict__ binE,
        const unsigned* __restrict__ cntN, const unsigned* __restrict__ cntE,
        const float* __restrict__ x,
        const float* __restrict__ W1, const float* __restrict__ b1,
        const float* __restrict__ W2, const float* __restrict__ b2,
        float* __restrict__ v1, float* __restrict__ v2, float* __restrict__ P_S,
        unsigned* __restrict__ bar, float* __restrict__ out) {
    __shared__ float    sBig[N_EDGES];      // 40 KB: v1/v2 stage OR edge-push accum
    __shared__ float    eS[NW][RE];         // per-wave edge accum
    __shared__ unsigned eC[NW][RE];
    __shared__ float    sS_n[RN];
    __shared__ unsigned sC_n[RN];
    __shared__ unsigned scntE[G1];
    __shared__ unsigned scntN[G1];
    __shared__ float    wgt[384];
    __shared__ float    y_loc[RN];

    const int b = blockIdx.x;
    const int t = threadIdx.x;
    const int wv = t >> 6;
    float my_binv = 0.0f;   // valid t < RE
    float my_dinv = 0.0f;   // valid t < RN

    // ---- Phase A: edge pass 1 -> v1 ----
    for (int j = t; j < NW * RE; j += BLK) { (&eS[0][0])[j] = 0.0f; (&eC[0][0])[j] = 0u; }
    if (t < G1) scntE[t] = cntE[(size_t)b * G1 + t];
    __syncthreads();
    {
        const unsigned* baseE = binE + (size_t)b * G1 * SLOT;
        for (int j = t; j < G1 * SLOT; j += BLK) {
            int s = j & (SLOT - 1), bb = j >> 6;
            if ((unsigned)s < scntE[bb]) {
                unsigned w = baseE[j];
                atomicAdd(&eS[wv][w >> 17], x[w & 0x1FFFFu]);
                atomicAdd(&eC[wv][w >> 17], 1u);
            }
        }
        __syncthreads();
        if (t < RE) {
            float s = 0.0f; unsigned c = 0u;
            #pragma unroll
            for (int k = 0; k < NW; ++k) { s += eS[k][t]; c += eC[k][t]; }
            my_binv = (c > 0u) ? (1.0f / (float)c) : 0.0f;
            st_a(&v1[b * RE + t], s * my_binv);
        }
    }
    bar_arrive(bar, 0);
    // prep B (overlapped with other blocks' phase A)
    if (t < RN) { sS_n[t] = 0.0f; sC_n[t] = 0u; }
    if (t < G1) scntN[t] = cntN[(size_t)b * G1 + t];
    if (t < 128) { wgt[t] = W1[t]; wgt[128 + t] = b1[t]; wgt[256 + t] = W2[t]; }
    bar_wait(bar, 0);

    // ---- Phase B: node pass 1 + MLP (y stays in LDS) + push to edge partials ----
    const unsigned* baseN = binN + (size_t)b * G1 * SLOT;
    for (int j = t; j < N_EDGES; j += BLK) sBig[j] = ld_a(&v1[j]);
    __syncthreads();
    for (int j = t; j < G1 * SLOT; j += BLK) {
        int s = j & (SLOT - 1), bb = j >> 6;
        if ((unsigned)s < scntN[bb]) {
            unsigned w = baseN[j];
            atomicAdd(&sS_n[w >> 14], sBig[w & 0x3FFFu]);
            atomicAdd(&sC_n[w >> 14], 1u);
        }
    }
    __syncthreads();
    if (t < RN) {
        unsigned c = sC_n[t];
        my_dinv = (c > 0u) ? (1.0f / (float)c) : 0.0f;
        float tt = sS_n[t] * my_dinv;
        float acc = 0.0f;
        #pragma unroll
        for (int f = 0; f < 128; ++f) {
            float h = fmaf(tt, wgt[f], wgt[128 + f]);
            h = fmaxf(h, 0.0f);
            acc = fmaf(h, wgt[256 + f], acc);
        }
        y_loc[t] = acc;
    }
    __syncthreads();
    for (int j = t; j < N_EDGES; j += BLK) sBig[j] = 0.0f;   // now edge-push accum
    __syncthreads();
    for (int j = t; j < G1 * SLOT; j += BLK) {
        int s = j & (SLOT - 1), bb = j >> 6;
        if ((unsigned)s < scntN[bb]) {
            unsigned w = baseN[j];
            atomicAdd(&sBig[w & 0x3FFFu], y_loc[w >> 14]);
        }
    }
    __syncthreads();
    {
        float* ps = P_S + (size_t)b * N_EDGES;
        for (int j = t; j < N_EDGES; j += BLK) st_a(&ps[j], sBig[j]);
    }
    bar_arrive(bar, 1);
    bar_wait(bar, 1);

    // ---- Phase C: reduce edge partials -> v2 (register accumulation) ----
    {
        const int lane = t & 63;
        if (lane < RE) {
            float acc = 0.0f;
            for (int g = wv; g < GF; g += NW)
                acc += ld_a(&P_S[(size_t)g * N_EDGES + b * RE + lane]);
            eS[wv][lane] = acc;
        }
    }
    __syncthreads();
    if (t < RE) {
        float s = 0.0f;
        #pragma unroll
        for (int k = 0; k < NW; ++k) s += eS[k][t];
        st_a(&v2[b * RE + t], s * my_binv);
    }
    bar_arrive(bar, 2);
    if (t < RN) sS_n[t] = 0.0f;   // prep D
    bar_wait(bar, 2);

    // ---- Phase D: node pass 2 + bias -> out ----
    for (int j = t; j < N_EDGES; j += BLK) sBig[j] = ld_a(&v2[j]);
    __syncthreads();
    for (int j = t; j < G1 * SLOT; j += BLK) {
        int s = j & (SLOT - 1), bb = j >> 6;
        if ((unsigned)s < scntN[bb]) {
            unsigned w = baseN[j];
            atomicAdd(&sS_n[w >> 14], sBig[w & 0x3FFFu]);
        }
    }
    __syncthreads();
    if (t < RN) out[b * RN + t] = fmaf(sS_n[t], my_dinv, b2[0]);
}

extern "C" void kernel_launch(void* const* d_in, const int* in_sizes, int n_in,
                              void* d_out, int out_size, void* d_ws, size_t ws_size,
                              hipStream_t stream) {
    const float* x    = (const float*)d_in[0];
    const float* W1   = (const float*)d_in[1];
    const float* b1   = (const float*)d_in[2];
    const float* W2   = (const float*)d_in[3];
    const float* b2   = (const float*)d_in[4];
    const int*   nidx = (const int*)d_in[5];
    const int*   eidx = (const int*)d_in[6];
    float*       out  = (float*)d_out;

    char* ws = (char*)d_ws;
    unsigned* binN = (unsigned*)(ws + 0);
    unsigned* binE = (unsigned*)(ws + 16384000);
    unsigned* cntN = (unsigned*)(ws + 32768000);
    unsigned* cntE = (unsigned*)(ws + 33024000);
    float*    v1   = (float*)(ws + 33280000);
    float*    v2   = (float*)(ws + 33320000);
    float*    P_S  = (float*)(ws + 33360000);
    unsigned* bar  = (unsigned*)(ws + 43360000);

    k_bin  <<<G1, BLK, 0, stream>>>(nidx, eidx, binN, binE, cntN, cntE, bar);
    k_fused<<<GF, BLK, 0, stream>>>(binN, binE, cntN, cntE, x, W1, b1, W2, b2,
                                    v1, v2, P_S, bar, out);
}

// Round 13
// 75.468 us; speedup vs baseline: 1.8695x; 1.1264x over previous
//
#include <hip/hip_runtime.h>

static constexpr int N_NODES = 100000;
static constexpr int N_EDGES = 10000;
static constexpr int NNZ     = 1600000;

static constexpr int G1    = 256;          // K1 blocks
static constexpr int CHUNK = NNZ / G1;     // 6250
static constexpr int NRN   = 250;          // node ranges (= GF)
static constexpr int RN    = 400;          // nodes per range
static constexpr int RE    = 40;           // edges per K2 block (250*40 = 10000)
static constexpr int SLOT  = 64;           // binN entries per (range, block) slot
static constexpr int BLK   = 1024;
static constexpr int NW    = 16;           // waves per block
static constexpr int GF    = 250;          // K2 grid
static constexpr int ITER  = G1 * SLOT / BLK;  // 16 binN entries per thread

// ---------------- ws layout (bytes) ----------------
// binN @ 0          : NRN*G1*SLOT u32 = 16,384,000
// cntN @ 16,384,000 : NRN*G1 u32      = 256,000
// P_S1 @ 16,640,000 : G1*N_EDGES f    = 10,240,000   (edge x-sum partials, K1)
// P_B1 @ 26,880,000 : G1*N_EDGES/2 u32=  5,120,000   (u16-packed count partials)
// v1   @ 32,000,000 : 40,000 ; v2 @ 32,040,000 : 40,000
// P_S  @ 32,080,000 : GF*N_EDGES f    = 10,000,000   (edge y-sum partials, K2)
// bar  @ 42,080,000 : 896 u32 (counters 3*8*32 + flags 3*32; reset by K1)

__device__ __forceinline__ void st_a(float* p, float v) {
    __hip_atomic_store(p, v, __ATOMIC_RELAXED, __HIP_MEMORY_SCOPE_AGENT);
}

__device__ __forceinline__ void bar_arrive(unsigned* bar, int phase) {
    __syncthreads();   // drains vmcnt: all prior sc1 stores are at L3
    if (threadIdx.x == 0)
        __hip_atomic_fetch_add(bar + phase * 256 + (blockIdx.x & 7) * 32, 1u,
                               __ATOMIC_RELAXED, __HIP_MEMORY_SCOPE_AGENT);
}
__device__ __forceinline__ void bar_wait(unsigned* bar, int phase) {
    if (threadIdx.x == 0) {
        unsigned* flag = bar + 768 + phase * 32;
        if (blockIdx.x == 0) {
            unsigned* cnt = bar + phase * 256;
            unsigned sum;
            do {
                __builtin_amdgcn_s_sleep(2);
                sum = 0u;
                #pragma unroll
                for (int g = 0; g < 8; ++g)
                    sum += __hip_atomic_load(cnt + g * 32, __ATOMIC_RELAXED,
                                             __HIP_MEMORY_SCOPE_AGENT);
            } while (sum < (unsigned)GF);
            __hip_atomic_store(flag, 1u, __ATOMIC_RELAXED, __HIP_MEMORY_SCOPE_AGENT);
        } else {
            while (__hip_atomic_load(flag, __ATOMIC_RELAXED,
                                     __HIP_MEMORY_SCOPE_AGENT) == 0u)
                __builtin_amdgcn_s_sleep(2);
        }
    }
    __syncthreads();
}

// K1: binN scatter + full-edge LDS aggregation of x (binE eliminated) + bar reset.
__global__ __launch_bounds__(BLK) void k_bin_agg(
        const int* __restrict__ nidx, const int* __restrict__ eidx,
        const float* __restrict__ x,
        unsigned* __restrict__ binN, unsigned* __restrict__ cntN,
        float* __restrict__ P_S1, unsigned* __restrict__ P_B1,
        unsigned* __restrict__ bar) {
    __shared__ float    sS[N_EDGES];      // 40 KB
    __shared__ unsigned sC[N_EDGES / 2];  // 20 KB (u16 pairs; <=6250/block, safe)
    __shared__ unsigned cN[NRN];          // 1 KB
    if (blockIdx.x == 0 && threadIdx.x < 896) bar[threadIdx.x] = 0u;
    for (int j = threadIdx.x; j < N_EDGES; j += BLK) sS[j] = 0.0f;
    for (int j = threadIdx.x; j < N_EDGES / 2; j += BLK) sC[j] = 0u;
    for (int j = threadIdx.x; j < NRN; j += BLK) cN[j] = 0u;
    __syncthreads();
    const int b = blockIdx.x;
    const int i0 = b * CHUNK, i1 = i0 + CHUNK;
    for (int i = i0 + threadIdx.x; i < i1; i += BLK) {
        int n = nidx[i], e = eidx[i];
        atomicAdd(&sS[e], x[n]);
        atomicAdd(&sC[e >> 1], 1u << ((e & 1) * 16));
        int rn = n / RN;                                   // magic-mul
        unsigned pn = atomicAdd(&cN[rn], 1u);
        binN[((size_t)rn * G1 + b) * SLOT + pn] = ((unsigned)(n - rn * RN) << 14) | (unsigned)e;
    }
    __syncthreads();
    for (int j = threadIdx.x; j < NRN; j += BLK) cntN[(size_t)j * G1 + b] = cN[j];
    float*    ps = P_S1 + (size_t)b * N_EDGES;
    unsigned* pb = P_B1 + (size_t)b * (N_EDGES / 2);
    for (int j = threadIdx.x; j < N_EDGES; j += BLK) ps[j] = sS[j];
    for (int j = threadIdx.x; j < N_EDGES / 2; j += BLK) pb[j] = sC[j];
}

// K2: A'(partial reduce -> v1) |bar| B(node1+MLP+push) |bar| C(reduce -> v2) |bar| D(node2)
__global__ __launch_bounds__(BLK) void k_fused(
        const unsigned* __restrict__ binN, const unsigned* __restrict__ cntN,
        const float* __restrict__ P_S1, const unsigned* __restrict__ P_B1,
        const float* __restrict__ W1, const float* __restrict__ b1,
        const float* __restrict__ W2, const float* __restrict__ b2,
        float* __restrict__ v1, float* __restrict__ v2, float* __restrict__ P_S,
        unsigned* __restrict__ bar, float* __restrict__ out) {
    __shared__ float    sBig[N_EDGES];    // 40 KB: v1/v2 stage OR edge-push accum
    __shared__ float    eS[NW][RE];
    __shared__ unsigned eC[NW][RE];
    __shared__ float    sS_n[RN];
    __shared__ unsigned sC_n[RN];
    __shared__ unsigned scntN[G1];
    __shared__ float    wgt[384];
    __shared__ float    y_loc[RN];

    const int b = blockIdx.x;
    const int t = threadIdx.x;
    const int wv = t >> 6;
    const int lane = t & 63;
    float my_binv = 0.0f;   // valid t < RE
    float my_dinv = 0.0f;   // valid t < RN

    // ---- Phase A': reduce K1's edge partials -> v1 (Binv in register) ----
    if (lane < RE) {
        const int e = b * RE + lane;
        float s = 0.0f; unsigned c = 0u;
        for (int g = wv; g < G1; g += NW) {
            s += P_S1[(size_t)g * N_EDGES + e];
            c += (P_B1[(size_t)g * (N_EDGES / 2) + (e >> 1)] >> ((e & 1) * 16)) & 0xFFFFu;
        }
        eS[wv][lane] = s; eC[wv][lane] = c;
    }
    __syncthreads();
    if (t < RE) {
        float s = 0.0f; unsigned c = 0u;
        #pragma unroll
        for (int k = 0; k < NW; ++k) { s += eS[k][t]; c += eC[k][t]; }
        my_binv = (c > 0u) ? (1.0f / (float)c) : 0.0f;
        st_a(&v1[b * RE + t], s * my_binv);
    }
    bar_arrive(bar, 0);
    // prep B (overlaps other blocks' phase A')
    if (t < RN) { sS_n[t] = 0.0f; sC_n[t] = 0u; }
    if (t < G1) scntN[t] = cntN[(size_t)b * G1 + t];
    if (t < 128) { wgt[t] = W1[t]; wgt[128 + t] = b1[t]; wgt[256 + t] = W2[t]; }
    bar_wait(bar, 0);

    // ---- Phase B: node pass 1 (binN -> registers) + MLP + push to edge partials ----
    const unsigned* baseN = binN + (size_t)b * G1 * SLOT;
    for (int j = t; j < N_EDGES; j += BLK) sBig[j] = v1[j];   // plain cached loads
    __syncthreads();
    unsigned w_reg[ITER];
    #pragma unroll
    for (int it = 0; it < ITER; ++it) {
        const int j = t + it * BLK;
        const int s = j & (SLOT - 1), bb = j >> 6;
        unsigned w = 0xFFFFFFFFu;
        if ((unsigned)s < scntN[bb]) {
            w = baseN[j];
            atomicAdd(&sS_n[w >> 14], sBig[w & 0x3FFFu]);
            atomicAdd(&sC_n[w >> 14], 1u);
        }
        w_reg[it] = w;
    }
    __syncthreads();
    if (t < RN) {
        unsigned c = sC_n[t];
        my_dinv = (c > 0u) ? (1.0f / (float)c) : 0.0f;
        float tt = sS_n[t] * my_dinv;
        float acc = 0.0f;
        #pragma unroll
        for (int f = 0; f < 128; ++f) {
            float h = fmaf(tt, wgt[f], wgt[128 + f]);
            h = fmaxf(h, 0.0f);
            acc = fmaf(h, wgt[256 + f], acc);
        }
        y_loc[t] = acc;
    }
    __syncthreads();
    for (int j = t; j < N_EDGES; j += BLK) sBig[j] = 0.0f;    // becomes push accum
    __syncthreads();
    #pragma unroll
    for (int it = 0; it < ITER; ++it) {
        unsigned w = w_reg[it];
        if (w != 0xFFFFFFFFu) atomicAdd(&sBig[w & 0x3FFFu], y_loc[w >> 14]);
    }
    __syncthreads();
    {
        float* ps = P_S + (size_t)b * N_EDGES;
        for (int j = t; j < N_EDGES; j += BLK) st_a(&ps[j], sBig[j]);
    }
    bar_arrive(bar, 1);
    bar_wait(bar, 1);

    // ---- Phase C: reduce K2 edge partials -> v2 ----
    if (lane < RE) {
        float acc = 0.0f;
        for (int g = wv; g < GF; g += NW)
            acc += P_S[(size_t)g * N_EDGES + b * RE + lane];  // plain loads
        eS[wv][lane] = acc;
    }
    __syncthreads();
    if (t < RE) {
        float s = 0.0f;
        #pragma unroll
        for (int k = 0; k < NW; ++k) s += eS[k][t];
        st_a(&v2[b * RE + t], s * my_binv);
    }
    bar_arrive(bar, 2);
    if (t < RN) sS_n[t] = 0.0f;   // prep D
    bar_wait(bar, 2);

    // ---- Phase D: node pass 2 (register replay) + bias -> out ----
    for (int j = t; j < N_EDGES; j += BLK) sBig[j] = v2[j];   // plain cached loads
    __syncthreads();
    #pragma unroll
    for (int it = 0; it < ITER; ++it) {
        unsigned w = w_reg[it];
        if (w != 0xFFFFFFFFu) atomicAdd(&sS_n[w >> 14], sBig[w & 0x3FFFu]);
    }
    __syncthreads();
    if (t < RN) out[b * RN + t] = fmaf(sS_n[t], my_dinv, b2[0]);
}

extern "C" void kernel_launch(void* const* d_in, const int* in_sizes, int n_in,
                              void* d_out, int out_size, void* d_ws, size_t ws_size,
                              hipStream_t stream) {
    const float* x    = (const float*)d_in[0];
    const float* W1   = (const float*)d_in[1];
    const float* b1   = (const float*)d_in[2];
    const float* W2   = (const float*)d_in[3];
    const float* b2   = (const float*)d_in[4];
    const int*   nidx = (const int*)d_in[5];
    const int*   eidx = (const int*)d_in[6];
    float*       out  = (float*)d_out;

    char* ws = (char*)d_ws;
    unsigned* binN = (unsigned*)(ws + 0);
    unsigned* cntN = (unsigned*)(ws + 16384000);
    float*    P_S1 = (float*)(ws + 16640000);
    unsigned* P_B1 = (unsigned*)(ws + 26880000);
    float*    v1   = (float*)(ws + 32000000);
    float*    v2   = (float*)(ws + 32040000);
    float*    P_S  = (float*)(ws + 32080000);
    unsigned* bar  = (unsigned*)(ws + 42080000);

    k_bin_agg<<<G1, BLK, 0, stream>>>(nidx, eidx, x, binN, cntN, P_S1, P_B1, bar);
    k_fused  <<<GF, BLK, 0, stream>>>(binN, cntN, P_S1, P_B1, W1, b1, W2, b2,
                                      v1, v2, P_S, bar, out);
}